// Round 5
// baseline (204.148 us; speedup 1.0000x reference)
//
#include <hip/hip_runtime.h>
#include <cstdint>
#include <cstddef>

typedef unsigned long long u64;
typedef unsigned int u32;

#define A_TOT   8400
#define NCLS    80
#define KSLOT   1024
#define NCHUNK  9
#define TOPK_N  1000
#define MAXDET  300
#define OUT_STRIDE (MAXDET * 6)

// ---------- helpers ----------

// stepwise f32 sigmoid with correctly-rounded f32 exp (via f64):
// e = fl32(exp(-x)); s = 1/(1+e)   -- replicates np-f32 semantics
__device__ __forceinline__ float sig32(float x) {
#pragma clang fp contract(off)
    float e = (float)exp(-(double)x);
    float t = 1.0f + e;
    return 1.0f / t;
}

__device__ __forceinline__ u32 key_hi_from_score(float s) {
    u32 u = __float_as_uint(s);
    return (u & 0x80000000u) ? ~u : (u | 0x80000000u);
}
__device__ __forceinline__ float score_from_key_hi(u32 t) {
    u32 u = (t & 0x80000000u) ? (t ^ 0x80000000u) : ~t;
    return __uint_as_float(u);
}

__device__ __forceinline__ float4 f4max(float4 a, float4 b) {
#pragma clang fp contract(off)
    return make_float4(fmaxf(a.x,b.x), fmaxf(a.y,b.y), fmaxf(a.z,b.z), fmaxf(a.w,b.w));
}
__device__ __forceinline__ float4 f4sub(float4 a, float4 b) {
#pragma clang fp contract(off)
    return make_float4(a.x-b.x, a.y-b.y, a.z-b.z, a.w-b.w);
}
__device__ __forceinline__ float4 f4add(float4 a, float4 b) {
#pragma clang fp contract(off)
    return make_float4(a.x+b.x, a.y+b.y, a.z+b.z, a.w+b.w);
}
__device__ __forceinline__ float4 f4exp(float4 a) {
#pragma clang fp contract(off)
    return make_float4(expf(a.x), expf(a.y), expf(a.z), expf(a.w));
}
__device__ __forceinline__ float4 f4div(float4 a, float4 b) {
#pragma clang fp contract(off)
    return make_float4(a.x/b.x, a.y/b.y, a.z/b.z, a.w/b.w);
}

// ---------- 1. fused decode: 4 anchors/thread, float4 coalesced streaming ----------
// Per-anchor arithmetic identical to the scalar version (bit-exact); only the
// load schedule changed: 16 float4 loads batched in registers before use.
__global__ __launch_bounds__(64) void k_decode(const float* __restrict__ preds,
                                               u64* __restrict__ key_raw,
                                               float4* __restrict__ dbox) {
#pragma clang fp contract(off)
    int g = blockIdx.x * blockDim.x + threadIdx.x;   // anchor group of 4
    int b = blockIdx.y;
    if (g >= A_TOT / 4) return;
    int a0 = g * 4;
    const float* pc = preds + ((size_t)b * 144 + 64) * A_TOT + a0;   // cls channels
    const float* pd = preds + (size_t)b * 144 * A_TOT + a0;          // dfl channels

    // ----- class two-max tracking, 4 anchors in parallel -----
    float m[4]  = {-3.0e38f,-3.0e38f,-3.0e38f,-3.0e38f};
    float m2[4] = {-3.0e38f,-3.0e38f,-3.0e38f,-3.0e38f};
    int   jm[4] = {0,0,0,0};

    for (int cb = 0; cb < 5; ++cb) {
        float4 v[16];
#pragma unroll
        for (int r = 0; r < 16; ++r)
            v[r] = *(const float4*)(pc + (size_t)(cb*16 + r) * A_TOT);
#pragma unroll
        for (int r = 0; r < 16; ++r) {
            int c = cb*16 + r;
            float vv0 = v[r].x, vv1 = v[r].y, vv2 = v[r].z, vv3 = v[r].w;
            if (vv0 > m[0]) { m2[0] = m[0]; m[0] = vv0; jm[0] = c; } else if (vv0 > m2[0]) { m2[0] = vv0; }
            if (vv1 > m[1]) { m2[1] = m[1]; m[1] = vv1; jm[1] = c; } else if (vv1 > m2[1]) { m2[1] = vv1; }
            if (vv2 > m[2]) { m2[2] = m[2]; m[2] = vv2; jm[2] = c; } else if (vv2 > m2[2]) { m2[2] = vv2; }
            if (vv3 > m[3]) { m2[3] = m[3]; m[3] = vv3; jm[3] = c; } else if (vv3 > m2[3]) { m2[3] = vv3; }
        }
    }

    // ----- keys (slow exact path rare: tie-gap < 1e-4 or saturated sigmoid) -----
    u64 keys[4];
#pragma unroll
    for (int k = 0; k < 4; ++k) {
        int a = a0 + k;
        float conf; int cls = jm[k];
        if ((m[k] - m2[k]) < 1e-4f || m[k] > 7.0f) {
            float sb = -1.0f; int jb = 0;
            for (int c = 0; c < NCLS; ++c) {
                float s = sig32(pc[(size_t)c * A_TOT + k]);
                if (s > sb) { sb = s; jb = c; }
            }
            conf = sb; cls = jb;
        } else {
            conf = sig32(m[k]);
        }
        float score = (conf > 0.25f) ? conf : -1.0f;
        u32 hi = key_hi_from_score(score);
        u32 lo = ((0x3FFFu - (u32)a) << 7) | (u32)cls;   // idx asc tie-break + cls
        keys[k] = ((u64)hi << 32) | lo;
    }

    // ----- dense DFL decode, 4 anchors in parallel -----
    float4 dq[4];   // dq[q] = component k -> d[q] of anchor a0+k
#pragma unroll
    for (int q = 0; q < 4; ++q) {
        float4 x4[16];
#pragma unroll
        for (int r = 0; r < 16; ++r)
            x4[r] = *(const float4*)(pd + (size_t)(q*16 + r) * A_TOT);
        float4 mx = x4[0];
#pragma unroll
        for (int r = 1; r < 16; ++r) mx = f4max(mx, x4[r]);
        float4 s = make_float4(0.f, 0.f, 0.f, 0.f);
#pragma unroll
        for (int r = 0; r < 16; ++r) { x4[r] = f4exp(f4sub(x4[r], mx)); s = f4add(s, x4[r]); }
        float4 dd = make_float4(0.f, 0.f, 0.f, 0.f);
#pragma unroll
        for (int r = 0; r < 16; ++r) {
            float4 pr = f4div(x4[r], s);
            float rf = (float)r;
            dd.x = dd.x + pr.x * rf; dd.y = dd.y + pr.y * rf;
            dd.z = dd.z + pr.z * rf; dd.w = dd.w + pr.w * rf;
        }
        dq[q] = dd;
    }

#pragma unroll
    for (int k = 0; k < 4; ++k) {
        int a = a0 + k;
        int row, col; float stride;
        if (a < 6400)      { row = a / 80;          col = a % 80;          stride = 8.0f; }
        else if (a < 8000) { int aa = a - 6400; row = aa / 40; col = aa % 40; stride = 16.0f; }
        else               { int aa = a - 8000; row = aa / 20; col = aa % 20; stride = 32.0f; }
        float ax = (float)col + 0.5f;
        float ay = (float)row + 0.5f;
        float d0, d1, d2, d3;
        if      (k == 0) { d0 = dq[0].x; d1 = dq[1].x; d2 = dq[2].x; d3 = dq[3].x; }
        else if (k == 1) { d0 = dq[0].y; d1 = dq[1].y; d2 = dq[2].y; d3 = dq[3].y; }
        else if (k == 2) { d0 = dq[0].z; d1 = dq[1].z; d2 = dq[2].z; d3 = dq[3].z; }
        else             { d0 = dq[0].w; d1 = dq[1].w; d2 = dq[2].w; d3 = dq[3].w; }
        // exact reference op order
        float x1 = ax - d0, y1 = ay - d1;
        float x2 = ax + d2, y2 = ay + d3;
        float cx = (x1 + x2) / 2.0f, cy = (y1 + y2) / 2.0f;
        float w  = x2 - x1,          h  = y2 - y1;
        float4 db;
        db.x = cx * stride; db.y = cy * stride; db.z = w * stride; db.w = h * stride;
        dbox[(size_t)b * A_TOT + a] = db;
        key_raw[(size_t)b * A_TOT + a] = keys[k];
    }
}

// ---------- 2a. bitonic sort of 1024-chunks (descending) ----------
__global__ __launch_bounds__(1024) void k_chunksort(const u64* __restrict__ key_raw,
                                                    u64* __restrict__ key_sorted) {
    __shared__ u64 s[KSLOT];
    int b = blockIdx.y, ch = blockIdx.x, t = threadIdx.x;
    int a = ch * KSLOT + t;
    s[t] = (a < A_TOT) ? key_raw[(size_t)b * A_TOT + a] : 0ull;
    __syncthreads();
    for (int k = 2; k <= KSLOT; k <<= 1) {
        for (int j = k >> 1; j > 0; j >>= 1) {
            int ixj = t ^ j;
            if (ixj > t) {
                u64 x = s[t], y = s[ixj];
                bool descBlock = ((t & k) == 0);
                bool sw = descBlock ? (x < y) : (x > y);
                if (sw) { s[t] = y; s[ixj] = x; }
            }
            __syncthreads();
        }
    }
    key_sorted[((size_t)b * NCHUNK + ch) * KSLOT + t] = s[t];
}

// ---------- 2b. merge 9 sorted chunks -> top-1024 descending ----------
__global__ __launch_bounds__(1024) void k_merge(const u64* __restrict__ key_sorted,
                                                u64* __restrict__ topk) {
    __shared__ u64 R[KSLOT];
    __shared__ u64 C[KSLOT];
    int b = blockIdx.x, t = threadIdx.x;
    R[t] = key_sorted[((size_t)b * NCHUNK) * KSLOT + t];
    for (int ch = 1; ch < NCHUNK; ++ch) {
        C[t] = key_sorted[((size_t)b * NCHUNK + ch) * KSLOT + t];
        __syncthreads();
        u64 r = R[t];
        u64 c = C[(KSLOT - 1) - t];
        u64 nv = (r > c) ? r : c;       // top-1024 of union, bitonic
        __syncthreads();
        R[t] = nv;
        __syncthreads();
        for (int j = KSLOT >> 1; j >= 1; j >>= 1) {   // bitonic merge, descending
            int ixj = t ^ j;
            if (ixj > t) {
                u64 x = R[t], y = R[ixj];
                if (x < y) { R[t] = y; R[ixj] = x; }
            }
            __syncthreads();
        }
    }
    topk[(size_t)b * KSLOT + t] = R[t];
}

// ---------- 3. prep: gather dense dbox for top slots, corner boxes + areas ----------
__global__ void k_prep(const float4* __restrict__ dbox, const u64* __restrict__ topk,
                       float* __restrict__ tb, float* __restrict__ ob,
                       float* __restrict__ area, u32* __restrict__ validf) {
#pragma clang fp contract(off)
    int slot = blockIdx.x * blockDim.x + threadIdx.x;
    int b = blockIdx.y;
    if (slot >= KSLOT) return;
    size_t si = (size_t)b * KSLOT + slot;
    u64 key = topk[si];
    u32 hi = (u32)(key >> 32);
    u32 lo = (u32)key;
    bool valid = (slot < TOPK_N) && (hi & 0x80000000u);
    if (!valid) {
        tb[si*4+0]=0.f; tb[si*4+1]=0.f; tb[si*4+2]=0.f; tb[si*4+3]=0.f;
        ob[si*4+0]=0.f; ob[si*4+1]=0.f; ob[si*4+2]=0.f; ob[si*4+3]=0.f;
        area[si] = 0.f; validf[si] = 0u;
        return;
    }
    int a   = 0x3FFF - (int)((lo >> 7) & 0x3FFFu);
    int cls = (int)(lo & 0x7Fu);

    float4 db = dbox[(size_t)b * A_TOT + a];
    float bx1 = db.x - db.z / 2.0f, by1 = db.y - db.w / 2.0f;
    float bx2 = db.x + db.z / 2.0f, by2 = db.y + db.w / 2.0f;
    tb[si*4+0] = bx1; tb[si*4+1] = by1; tb[si*4+2] = bx2; tb[si*4+3] = by2;

    float off = (float)cls * 7680.0f;
    float o0 = bx1 + off, o1 = by1 + off, o2 = bx2 + off, o3 = by2 + off;
    ob[si*4+0] = o0; ob[si*4+1] = o1; ob[si*4+2] = o2; ob[si*4+3] = o3;
    area[si] = (o2 - o0) * (o3 - o1);
    validf[si] = 1u;
}

// ---------- 4. suppression bitmask matrix: row i, bits j>i with iou>thr ----------
// Lane assignment: lanes of a wave hold consecutive i (register-resident bi),
// w is wave-uniform -> inner-loop sob[j]/sar[j] reads are LDS broadcasts
// (zero bank conflicts). Word-blocks fully below the diagonal are skipped.
__global__ __launch_bounds__(256) void k_matrix(const float* __restrict__ ob,
                                                const float* __restrict__ area,
                                                u64* __restrict__ masks) {
#pragma clang fp contract(off)
    __shared__ float4 sob[KSLOT];
    __shared__ float  sar[KSLOT];
    int b = blockIdx.y, rblk = blockIdx.x, tid = threadIdx.x;
    const float4* gob = (const float4*)(ob + (size_t)b * KSLOT * 4);
    const float*  gar = area + (size_t)b * KSLOT;
    for (int i = tid; i < KSLOT; i += blockDim.x) { sob[i] = gob[i]; sar[i] = gar[i]; }
    __syncthreads();

    int lane = tid & 63;
    int wave = tid >> 6;               // 0..3
    int i = rblk * 64 + lane;
    float4 bi = sob[i];
    float Ai = sar[i];

#pragma unroll
    for (int wl = 0; wl < 4; ++wl) {
        int w = wave * 4 + wl;         // wave-uniform word index 0..15
        u64 mword = 0ull;
        if (w >= rblk) {               // whole word below diagonal -> all zero
            for (int bit = 0; bit < 64; ++bit) {
                int j = (w << 6) + bit;
                float4 bj = sob[j];    // broadcast (uniform addr across wave)
                float Aj = sar[j];     // broadcast
                float lt0 = fmaxf(bi.x, bj.x);
                float lt1 = fmaxf(bi.y, bj.y);
                float rb0 = fminf(bi.z, bj.z);
                float rb1 = fminf(bi.w, bj.w);
                float ww = fmaxf(rb0 - lt0, 0.0f);
                float hh = fmaxf(rb1 - lt1, 0.0f);
                float inter = ww * hh;
                float den = ((Ai + Aj) - inter) + 1e-7f;
                float iou = inter / den;
                if ((j > i) && (iou > 0.45f)) mword |= (1ull << bit);
            }
        }
        masks[((size_t)b * KSLOT + i) * 16 + w] = mword;
    }
}

// ---------- 5. greedy scan: live-mask skip, LDS-staged rows, early stop ----------
// Trip count = number of KEPT boxes (<= 300), not number of candidates.
// Key fact: the lowest live bit is always kept (all earlier kept rows' masks
// already applied), so each serial step commits exactly one kept box.
__global__ __launch_bounds__(64) void k_scan(const u64* __restrict__ masks,
                                             const u32* __restrict__ validf,
                                             u64* __restrict__ keep) {
    __shared__ u64 rows[KSLOT];          // 8KB: current word's 64 rows x 16 words
    int b = blockIdx.x, lane = threadIdx.x;
    const char* base = (const char*)(masks + (size_t)b * KSLOT * 16);

    // prefetch word 0's 8KB block into registers (coalesced dwordx4)
    float4 r0, r1, r2, r3, r4, r5, r6, r7;
    {
        const float4* src = (const float4*)base;
        r0 = src[0*64 + lane]; r1 = src[1*64 + lane];
        r2 = src[2*64 + lane]; r3 = src[3*64 + lane];
        r4 = src[4*64 + lane]; r5 = src[5*64 + lane];
        r6 = src[6*64 + lane]; r7 = src[7*64 + lane];
    }

    u64 kw = 0ull;       // lane l<16 owns keep word l
    u64 rem = 0ull;      // lane l<16 owns removed word l
    int kept = 0;

    for (int w = 0; w < 16; ++w) {
        // stage current word's rows into LDS
        {
            float4* dst = (float4*)rows;
            dst[0*64 + lane] = r0; dst[1*64 + lane] = r1;
            dst[2*64 + lane] = r2; dst[3*64 + lane] = r3;
            dst[4*64 + lane] = r4; dst[5*64 + lane] = r5;
            dst[6*64 + lane] = r6; dst[7*64 + lane] = r7;
        }
        u32 vf = validf[(size_t)b * KSLOT + w * 64 + lane];
        u64 valid_w = __ballot(vf != 0u);
        __syncthreads();
        // issue next word's loads (overlap with the serial scan below)
        if (w < 15) {
            const float4* src = (const float4*)(base + (size_t)(w + 1) * 8192);
            r0 = src[0*64 + lane]; r1 = src[1*64 + lane];
            r2 = src[2*64 + lane]; r3 = src[3*64 + lane];
            r4 = src[4*64 + lane]; r5 = src[5*64 + lane];
            r6 = src[6*64 + lane]; r7 = src[7*64 + lane];
        }

        u64 live = valid_w & ~__shfl(rem, w);
        while (live) {
            int i = __ffsll(live) - 1;           // lowest live slot: always kept
            if (lane == w) kw |= (1ull << i);
            u64 m = (lane < 16) ? rows[i * 16 + lane] : 0ull;
            rem |= m;
            ++kept;
            if (kept >= MAXDET) break;           // only first 300 kept are emitted
            live &= ~(__shfl(m, w) | (1ull << i));
        }
        if (kept >= MAXDET) break;
        __syncthreads();   // all lanes done reading rows before next overwrite
    }
    if (lane < 16) keep[(size_t)b * 16 + lane] = kw;
}

// ---------- 6. finalize: compact kept (ordered) into first 300 rows ----------
__global__ __launch_bounds__(1024) void k_final(const u64* __restrict__ keep,
                                                const u64* __restrict__ topk,
                                                const float* __restrict__ tb,
                                                float* __restrict__ out) {
    __shared__ u64 kw[16];
    __shared__ int pref[16];
    int b = blockIdx.x, t = threadIdx.x;
    float* ob_ = out + (size_t)b * OUT_STRIDE;
    for (int i = t; i < OUT_STRIDE; i += blockDim.x) ob_[i] = 0.0f;
    if (t < 16) kw[t] = keep[(size_t)b * 16 + t];
    __syncthreads();
    if (t == 0) {
        int s = 0;
        for (int w = 0; w < 16; ++w) { pref[w] = s; s += __popcll(kw[w]); }
    }
    __syncthreads();
    int w = t >> 6, bit = t & 63;
    bool kp = (kw[w] >> bit) & 1ull;
    if (kp) {
        u64 below = (bit == 0) ? 0ull : (kw[w] & ((1ull << bit) - 1ull));
        int rank = pref[w] + __popcll(below);
        if (rank < MAXDET) {
            size_t si = (size_t)b * KSLOT + t;
            u64 key = topk[si];
            u32 hi = (u32)(key >> 32);
            u32 lo = (u32)key;
            float score = score_from_key_hi(hi);
            float clsf = (float)(lo & 0x7Fu);
            float* o = ob_ + rank * 6;
            o[0] = tb[si*4+0]; o[1] = tb[si*4+1];
            o[2] = tb[si*4+2]; o[3] = tb[si*4+3];
            o[4] = score; o[5] = clsf;
        }
    }
}

// ---------- launch ----------
extern "C" void kernel_launch(void* const* d_in, const int* in_sizes, int n_in,
                              void* d_out, int out_size, void* d_ws, size_t ws_size,
                              hipStream_t stream) {
    const float* preds = (const float*)d_in[0];
    float* out = (float*)d_out;
    int B = in_sizes[0] / (144 * A_TOT);

    char* ws = (char*)d_ws;
    size_t off = 0;
    u64* key_raw    = (u64*)(ws + off); off += (size_t)B * A_TOT * 8;
    u64* key_sorted = (u64*)(ws + off); off += (size_t)B * NCHUNK * KSLOT * 8;
    u64* topk       = (u64*)(ws + off); off += (size_t)B * KSLOT * 8;
    float4* dbox    = (float4*)(ws + off); off += (size_t)B * A_TOT * 16;
    float* tb       = (float*)(ws + off); off += (size_t)B * KSLOT * 4 * 4;
    float* obuf     = (float*)(ws + off); off += (size_t)B * KSLOT * 4 * 4;
    float* area     = (float*)(ws + off); off += (size_t)B * KSLOT * 4;
    u32* validf     = (u32*)(ws + off); off += (size_t)B * KSLOT * 4;
    u64* masks      = (u64*)(ws + off); off += (size_t)B * KSLOT * 16 * 8;
    u64* keep       = (u64*)(ws + off); off += (size_t)B * 16 * 8;

    k_decode<<<dim3((A_TOT/4 + 63) / 64, B), 64, 0, stream>>>(preds, key_raw, dbox);
    k_chunksort<<<dim3(NCHUNK, B), KSLOT, 0, stream>>>(key_raw, key_sorted);
    k_merge<<<B, KSLOT, 0, stream>>>(key_sorted, topk);
    k_prep<<<dim3(KSLOT / 256, B), 256, 0, stream>>>(dbox, topk, tb, obuf, area, validf);
    k_matrix<<<dim3(16, B), 256, 0, stream>>>(obuf, area, masks);
    k_scan<<<B, 64, 0, stream>>>(masks, validf, keep);
    k_final<<<B, 1024, 0, stream>>>(keep, topk, tb, out);
}

// Round 6
// 167.944 us; speedup vs baseline: 1.2156x; 1.2156x over previous
//
#include <hip/hip_runtime.h>
#include <cstdint>
#include <cstddef>

typedef unsigned long long u64;
typedef unsigned int u32;

#define A_TOT   8400
#define NCLS    80
#define KSLOT   1024
#define NCHUNK  9
#define TOPK_N  1000
#define MAXDET  300
#define OUT_STRIDE (MAXDET * 6)

// ---------- helpers ----------

// stepwise f32 sigmoid with correctly-rounded f32 exp (via f64):
// e = fl32(exp(-x)); s = 1/(1+e)   -- replicates np-f32 semantics
__device__ __forceinline__ float sig32(float x) {
#pragma clang fp contract(off)
    float e = (float)exp(-(double)x);
    float t = 1.0f + e;
    return 1.0f / t;
}

__device__ __forceinline__ u32 key_hi_from_score(float s) {
    u32 u = __float_as_uint(s);
    return (u & 0x80000000u) ? ~u : (u | 0x80000000u);
}
__device__ __forceinline__ float score_from_key_hi(u32 t) {
    u32 u = (t & 0x80000000u) ? (t ^ 0x80000000u) : ~t;
    return __uint_as_float(u);
}

// ---------- 1. fused decode: LDS-transpose staging, 1 anchor/thread ----------
// Grid: 33x32 blocks x 256 thr = 4200 waves (~4.1/SIMD TLP). Channels staged
// 16 at a time into LDS via coalesced float4 loads, double-buffered so chunk
// k+1's HBM latency hides under chunk k's softmax/two-max VALU. LDS column
// reads are stride-256 floats = 2 lanes/bank = conflict-free.
__global__ __launch_bounds__(256) void k_decode(const float* __restrict__ preds,
                                                u64* __restrict__ key_raw,
                                                float4* __restrict__ dbox) {
#pragma clang fp contract(off)
    __shared__ float tile[2][16][256];
    int b = blockIdx.y;
    int a0 = blockIdx.x * 256;
    int t = threadIdx.x;
    int a = a0 + t;
    int nA = A_TOT - a0; if (nA > 256) nA = 256;
    int p4max = nA >> 2;                       // valid float4s per channel row
    const float* pb = preds + (size_t)b * 144 * A_TOT;

    // staging map: float4 index f = t + 256k -> row r=f>>6 (channel), pos p=f&63
    int sr[4], sp[4];
#pragma unroll
    for (int k = 0; k < 4; ++k) { int f = t + 256 * k; sr[k] = f >> 6; sp[k] = f & 63; }

    float4 regs[4];
    auto gload = [&](int ch0) {
#pragma unroll
        for (int k = 0; k < 4; ++k) {
            if (sp[k] < p4max)
                regs[k] = *(const float4*)(pb + (size_t)(ch0 + sr[k]) * A_TOT + a0 + 4 * sp[k]);
            else
                regs[k] = make_float4(0.f, 0.f, 0.f, 0.f);
        }
    };
    auto dswrite = [&](int buf) {
#pragma unroll
        for (int k = 0; k < 4; ++k)
            *(float4*)&tile[buf][sr[k]][4 * sp[k]] = regs[k];
    };

    float d[4] = {0.f, 0.f, 0.f, 0.f};
    float m = -3.0e38f, m2 = -3.0e38f;
    int jm = 0;

    gload(0); dswrite(0); __syncthreads();
    gload(16);                                  // chunk 1 in flight under chunk 0

    for (int cb = 0; cb < 9; ++cb) {
        int buf = cb & 1;
        if (t < nA) {
            float x[16];
#pragma unroll
            for (int r = 0; r < 16; ++r) x[r] = tile[buf][r][t];
            if (cb < 4) {
                // DFL softmax-expectation, exact reference op order
                float mx = x[0];
#pragma unroll
                for (int r = 1; r < 16; ++r) mx = fmaxf(mx, x[r]);
                float e[16], s = 0.f;
#pragma unroll
                for (int r = 0; r < 16; ++r) { e[r] = expf(x[r] - mx); s = s + e[r]; }
                float dd = 0.f;
#pragma unroll
                for (int r = 0; r < 16; ++r) { float pr = e[r] / s; dd = dd + pr * (float)r; }
                d[cb] = dd;
            } else {
                int cbase = (cb - 4) * 16;
#pragma unroll
                for (int r = 0; r < 16; ++r) {
                    int c = cbase + r;
                    float v = x[r];
                    if (v > m) { m2 = m; m = v; jm = c; }
                    else if (v > m2) { m2 = v; }
                }
            }
        }
        if (cb + 1 < 9) {
            __syncthreads();                    // all readers of buf[(cb+1)&1] done
            dswrite((cb + 1) & 1);
            if (cb + 2 < 9) gload((cb + 2) * 16);
            __syncthreads();
        }
    }

    if (t >= nA) return;

    // ----- key (slow exact path rare: tie-gap < 1e-4 or saturated sigmoid) -----
    const float* pc = pb + (size_t)64 * A_TOT + a;
    float conf; int cls = jm;
    if ((m - m2) < 1e-4f || m > 7.0f) {
        float sb = -1.0f; int jb = 0;
        for (int c = 0; c < NCLS; ++c) {
            float s = sig32(pc[(size_t)c * A_TOT]);
            if (s > sb) { sb = s; jb = c; }
        }
        conf = sb; cls = jb;
    } else {
        conf = sig32(m);
    }
    float score = (conf > 0.25f) ? conf : -1.0f;
    u32 hi = key_hi_from_score(score);
    u32 lo = ((0x3FFFu - (u32)a) << 7) | (u32)cls;   // idx asc tie-break + cls
    key_raw[(size_t)b * A_TOT + a] = ((u64)hi << 32) | lo;

    // ----- box from d[0..3], exact reference op order -----
    int row, col; float stride;
    if (a < 6400)      { row = a / 80;          col = a % 80;          stride = 8.0f; }
    else if (a < 8000) { int aa = a - 6400; row = aa / 40; col = aa % 40; stride = 16.0f; }
    else               { int aa = a - 8000; row = aa / 20; col = aa % 20; stride = 32.0f; }
    float ax = (float)col + 0.5f;
    float ay = (float)row + 0.5f;
    float x1 = ax - d[0], y1 = ay - d[1];
    float x2 = ax + d[2], y2 = ay + d[3];
    float cx = (x1 + x2) / 2.0f, cy = (y1 + y2) / 2.0f;
    float w  = x2 - x1,          h  = y2 - y1;
    float4 db;
    db.x = cx * stride; db.y = cy * stride; db.z = w * stride; db.w = h * stride;
    dbox[(size_t)b * A_TOT + a] = db;
}

// ---------- 2a. bitonic sort of 1024-chunks (descending) ----------
__global__ __launch_bounds__(1024) void k_chunksort(const u64* __restrict__ key_raw,
                                                    u64* __restrict__ key_sorted) {
    __shared__ u64 s[KSLOT];
    int b = blockIdx.y, ch = blockIdx.x, t = threadIdx.x;
    int a = ch * KSLOT + t;
    s[t] = (a < A_TOT) ? key_raw[(size_t)b * A_TOT + a] : 0ull;
    __syncthreads();
    for (int k = 2; k <= KSLOT; k <<= 1) {
        for (int j = k >> 1; j > 0; j >>= 1) {
            int ixj = t ^ j;
            if (ixj > t) {
                u64 x = s[t], y = s[ixj];
                bool descBlock = ((t & k) == 0);
                bool sw = descBlock ? (x < y) : (x > y);
                if (sw) { s[t] = y; s[ixj] = x; }
            }
            __syncthreads();
        }
    }
    key_sorted[((size_t)b * NCHUNK + ch) * KSLOT + t] = s[t];
}

// ---------- 2b. merge 9 sorted chunks -> top-1024 descending ----------
__global__ __launch_bounds__(1024) void k_merge(const u64* __restrict__ key_sorted,
                                                u64* __restrict__ topk) {
    __shared__ u64 R[KSLOT];
    __shared__ u64 C[KSLOT];
    int b = blockIdx.x, t = threadIdx.x;
    R[t] = key_sorted[((size_t)b * NCHUNK) * KSLOT + t];
    for (int ch = 1; ch < NCHUNK; ++ch) {
        C[t] = key_sorted[((size_t)b * NCHUNK + ch) * KSLOT + t];
        __syncthreads();
        u64 r = R[t];
        u64 c = C[(KSLOT - 1) - t];
        u64 nv = (r > c) ? r : c;       // top-1024 of union, bitonic
        __syncthreads();
        R[t] = nv;
        __syncthreads();
        for (int j = KSLOT >> 1; j >= 1; j >>= 1) {   // bitonic merge, descending
            int ixj = t ^ j;
            if (ixj > t) {
                u64 x = R[t], y = R[ixj];
                if (x < y) { R[t] = y; R[ixj] = x; }
            }
            __syncthreads();
        }
    }
    topk[(size_t)b * KSLOT + t] = R[t];
}

// ---------- 3. prep: gather dense dbox for top slots, corner boxes + areas ----------
__global__ void k_prep(const float4* __restrict__ dbox, const u64* __restrict__ topk,
                       float* __restrict__ tb, float* __restrict__ ob,
                       float* __restrict__ area, u32* __restrict__ validf) {
#pragma clang fp contract(off)
    int slot = blockIdx.x * blockDim.x + threadIdx.x;
    int b = blockIdx.y;
    if (slot >= KSLOT) return;
    size_t si = (size_t)b * KSLOT + slot;
    u64 key = topk[si];
    u32 hi = (u32)(key >> 32);
    u32 lo = (u32)key;
    bool valid = (slot < TOPK_N) && (hi & 0x80000000u);
    if (!valid) {
        tb[si*4+0]=0.f; tb[si*4+1]=0.f; tb[si*4+2]=0.f; tb[si*4+3]=0.f;
        ob[si*4+0]=0.f; ob[si*4+1]=0.f; ob[si*4+2]=0.f; ob[si*4+3]=0.f;
        area[si] = 0.f; validf[si] = 0u;
        return;
    }
    int a   = 0x3FFF - (int)((lo >> 7) & 0x3FFFu);
    int cls = (int)(lo & 0x7Fu);

    float4 db = dbox[(size_t)b * A_TOT + a];
    float bx1 = db.x - db.z / 2.0f, by1 = db.y - db.w / 2.0f;
    float bx2 = db.x + db.z / 2.0f, by2 = db.y + db.w / 2.0f;
    tb[si*4+0] = bx1; tb[si*4+1] = by1; tb[si*4+2] = bx2; tb[si*4+3] = by2;

    float off = (float)cls * 7680.0f;
    float o0 = bx1 + off, o1 = by1 + off, o2 = bx2 + off, o3 = by2 + off;
    ob[si*4+0] = o0; ob[si*4+1] = o1; ob[si*4+2] = o2; ob[si*4+3] = o3;
    area[si] = (o2 - o0) * (o3 - o1);
    validf[si] = 1u;
}

// ---------- 4. suppression bitmask matrix: row i, bits j>i with iou>thr ----------
// Lane assignment: lanes of a wave hold consecutive i (register-resident bi),
// w is wave-uniform -> inner-loop sob[j]/sar[j] reads are LDS broadcasts
// (zero bank conflicts). Word-blocks fully below the diagonal are skipped.
__global__ __launch_bounds__(256) void k_matrix(const float* __restrict__ ob,
                                                const float* __restrict__ area,
                                                u64* __restrict__ masks) {
#pragma clang fp contract(off)
    __shared__ float4 sob[KSLOT];
    __shared__ float  sar[KSLOT];
    int b = blockIdx.y, rblk = blockIdx.x, tid = threadIdx.x;
    const float4* gob = (const float4*)(ob + (size_t)b * KSLOT * 4);
    const float*  gar = area + (size_t)b * KSLOT;
    for (int i = tid; i < KSLOT; i += blockDim.x) { sob[i] = gob[i]; sar[i] = gar[i]; }
    __syncthreads();

    int lane = tid & 63;
    int wave = tid >> 6;               // 0..3
    int i = rblk * 64 + lane;
    float4 bi = sob[i];
    float Ai = sar[i];

#pragma unroll
    for (int wl = 0; wl < 4; ++wl) {
        int w = wave * 4 + wl;         // wave-uniform word index 0..15
        u64 mword = 0ull;
        if (w >= rblk) {               // whole word below diagonal -> all zero
            for (int bit = 0; bit < 64; ++bit) {
                int j = (w << 6) + bit;
                float4 bj = sob[j];    // broadcast (uniform addr across wave)
                float Aj = sar[j];     // broadcast
                float lt0 = fmaxf(bi.x, bj.x);
                float lt1 = fmaxf(bi.y, bj.y);
                float rb0 = fminf(bi.z, bj.z);
                float rb1 = fminf(bi.w, bj.w);
                float ww = fmaxf(rb0 - lt0, 0.0f);
                float hh = fmaxf(rb1 - lt1, 0.0f);
                float inter = ww * hh;
                float den = ((Ai + Aj) - inter) + 1e-7f;
                float iou = inter / den;
                if ((j > i) && (iou > 0.45f)) mword |= (1ull << bit);
            }
        }
        masks[((size_t)b * KSLOT + i) * 16 + w] = mword;
    }
}

// ---------- 5. greedy scan: live-mask skip, LDS-staged rows, early stop ----------
// Trip count = number of KEPT boxes (<= 300), not number of candidates.
// Key fact: the lowest live bit is always kept (all earlier kept rows' masks
// already applied), so each serial step commits exactly one kept box.
__global__ __launch_bounds__(64) void k_scan(const u64* __restrict__ masks,
                                             const u32* __restrict__ validf,
                                             u64* __restrict__ keep) {
    __shared__ u64 rows[KSLOT];          // 8KB: current word's 64 rows x 16 words
    int b = blockIdx.x, lane = threadIdx.x;
    const char* base = (const char*)(masks + (size_t)b * KSLOT * 16);

    // prefetch word 0's 8KB block into registers (coalesced dwordx4)
    float4 r0, r1, r2, r3, r4, r5, r6, r7;
    {
        const float4* src = (const float4*)base;
        r0 = src[0*64 + lane]; r1 = src[1*64 + lane];
        r2 = src[2*64 + lane]; r3 = src[3*64 + lane];
        r4 = src[4*64 + lane]; r5 = src[5*64 + lane];
        r6 = src[6*64 + lane]; r7 = src[7*64 + lane];
    }

    u64 kw = 0ull;       // lane l<16 owns keep word l
    u64 rem = 0ull;      // lane l<16 owns removed word l
    int kept = 0;

    for (int w = 0; w < 16; ++w) {
        // stage current word's rows into LDS
        {
            float4* dst = (float4*)rows;
            dst[0*64 + lane] = r0; dst[1*64 + lane] = r1;
            dst[2*64 + lane] = r2; dst[3*64 + lane] = r3;
            dst[4*64 + lane] = r4; dst[5*64 + lane] = r5;
            dst[6*64 + lane] = r6; dst[7*64 + lane] = r7;
        }
        u32 vf = validf[(size_t)b * KSLOT + w * 64 + lane];
        u64 valid_w = __ballot(vf != 0u);
        __syncthreads();
        // issue next word's loads (overlap with the serial scan below)
        if (w < 15) {
            const float4* src = (const float4*)(base + (size_t)(w + 1) * 8192);
            r0 = src[0*64 + lane]; r1 = src[1*64 + lane];
            r2 = src[2*64 + lane]; r3 = src[3*64 + lane];
            r4 = src[4*64 + lane]; r5 = src[5*64 + lane];
            r6 = src[6*64 + lane]; r7 = src[7*64 + lane];
        }

        u64 live = valid_w & ~__shfl(rem, w);
        while (live) {
            int i = __ffsll(live) - 1;           // lowest live slot: always kept
            if (lane == w) kw |= (1ull << i);
            u64 m = (lane < 16) ? rows[i * 16 + lane] : 0ull;
            rem |= m;
            ++kept;
            if (kept >= MAXDET) break;           // only first 300 kept are emitted
            live &= ~(__shfl(m, w) | (1ull << i));
        }
        if (kept >= MAXDET) break;
        __syncthreads();   // all lanes done reading rows before next overwrite
    }
    if (lane < 16) keep[(size_t)b * 16 + lane] = kw;
}

// ---------- 6. finalize: compact kept (ordered) into first 300 rows ----------
__global__ __launch_bounds__(1024) void k_final(const u64* __restrict__ keep,
                                                const u64* __restrict__ topk,
                                                const float* __restrict__ tb,
                                                float* __restrict__ out) {
    __shared__ u64 kw[16];
    __shared__ int pref[16];
    int b = blockIdx.x, t = threadIdx.x;
    float* ob_ = out + (size_t)b * OUT_STRIDE;
    for (int i = t; i < OUT_STRIDE; i += blockDim.x) ob_[i] = 0.0f;
    if (t < 16) kw[t] = keep[(size_t)b * 16 + t];
    __syncthreads();
    if (t == 0) {
        int s = 0;
        for (int w = 0; w < 16; ++w) { pref[w] = s; s += __popcll(kw[w]); }
    }
    __syncthreads();
    int w = t >> 6, bit = t & 63;
    bool kp = (kw[w] >> bit) & 1ull;
    if (kp) {
        u64 below = (bit == 0) ? 0ull : (kw[w] & ((1ull << bit) - 1ull));
        int rank = pref[w] + __popcll(below);
        if (rank < MAXDET) {
            size_t si = (size_t)b * KSLOT + t;
            u64 key = topk[si];
            u32 hi = (u32)(key >> 32);
            u32 lo = (u32)key;
            float score = score_from_key_hi(hi);
            float clsf = (float)(lo & 0x7Fu);
            float* o = ob_ + rank * 6;
            o[0] = tb[si*4+0]; o[1] = tb[si*4+1];
            o[2] = tb[si*4+2]; o[3] = tb[si*4+3];
            o[4] = score; o[5] = clsf;
        }
    }
}

// ---------- launch ----------
extern "C" void kernel_launch(void* const* d_in, const int* in_sizes, int n_in,
                              void* d_out, int out_size, void* d_ws, size_t ws_size,
                              hipStream_t stream) {
    const float* preds = (const float*)d_in[0];
    float* out = (float*)d_out;
    int B = in_sizes[0] / (144 * A_TOT);

    char* ws = (char*)d_ws;
    size_t off = 0;
    u64* key_raw    = (u64*)(ws + off); off += (size_t)B * A_TOT * 8;
    u64* key_sorted = (u64*)(ws + off); off += (size_t)B * NCHUNK * KSLOT * 8;
    u64* topk       = (u64*)(ws + off); off += (size_t)B * KSLOT * 8;
    float4* dbox    = (float4*)(ws + off); off += (size_t)B * A_TOT * 16;
    float* tb       = (float*)(ws + off); off += (size_t)B * KSLOT * 4 * 4;
    float* obuf     = (float*)(ws + off); off += (size_t)B * KSLOT * 4 * 4;
    float* area     = (float*)(ws + off); off += (size_t)B * KSLOT * 4;
    u32* validf     = (u32*)(ws + off); off += (size_t)B * KSLOT * 4;
    u64* masks      = (u64*)(ws + off); off += (size_t)B * KSLOT * 16 * 8;
    u64* keep       = (u64*)(ws + off); off += (size_t)B * 16 * 8;

    k_decode<<<dim3((A_TOT + 255) / 256, B), 256, 0, stream>>>(preds, key_raw, dbox);
    k_chunksort<<<dim3(NCHUNK, B), KSLOT, 0, stream>>>(key_raw, key_sorted);
    k_merge<<<B, KSLOT, 0, stream>>>(key_sorted, topk);
    k_prep<<<dim3(KSLOT / 256, B), 256, 0, stream>>>(dbox, topk, tb, obuf, area, validf);
    k_matrix<<<dim3(16, B), 256, 0, stream>>>(obuf, area, masks);
    k_scan<<<B, 64, 0, stream>>>(masks, validf, keep);
    k_final<<<B, 1024, 0, stream>>>(keep, topk, tb, out);
}

// Round 8
// 167.443 us; speedup vs baseline: 1.2192x; 1.0030x over previous
//
#include <hip/hip_runtime.h>
#include <cstdint>
#include <cstddef>

typedef unsigned long long u64;
typedef unsigned int u32;

#define A_TOT   8400
#define NCLS    80
#define KSLOT   1024
#define NCHUNK  9
#define TOPK_N  1000
#define MAXDET  300
#define OUT_STRIDE (MAXDET * 6)

// ---------- helpers ----------

// stepwise f32 sigmoid with correctly-rounded f32 exp (via f64):
// e = fl32(exp(-x)); s = 1/(1+e)   -- replicates np-f32 semantics
__device__ __forceinline__ float sig32(float x) {
#pragma clang fp contract(off)
    float e = (float)exp(-(double)x);
    float t = 1.0f + e;
    return 1.0f / t;
}

__device__ __forceinline__ u32 key_hi_from_score(float s) {
    u32 u = __float_as_uint(s);
    return (u & 0x80000000u) ? ~u : (u | 0x80000000u);
}
__device__ __forceinline__ float score_from_key_hi(u32 t) {
    u32 u = (t & 0x80000000u) ? (t ^ 0x80000000u) : ~t;
    return __uint_as_float(u);
}

// merge-path: element of rank t (0-based) in the descending merge of two
// descending length-1024 lists A, B (t < 1024). Values across A and B are
// distinct wherever it matters (unique anchor index in low bits; zero-pads
// only ever meet strictly-positive real keys), so strict '>' is exact.
__device__ __forceinline__ u64 mp_rank(const u64* __restrict__ A,
                                       const u64* __restrict__ B, int t) {
    int lo = 0, hi = t;
    while (lo < hi) {                     // find max i with (i==0 || A[i-1] > B[t-i])
        int mid = (lo + hi + 1) >> 1;
        if (A[mid - 1] > B[t - mid]) lo = mid; else hi = mid - 1;
    }
    int i = lo, j = t - lo;               // i,j <= t < 1024: A[i], B[j] always valid
    u64 av = A[i], bv = B[j];
    return av > bv ? av : bv;
}

// ---------- 1. fused decode: LDS-transpose staging, 1 anchor/thread ----------
// Grid: 33x32 blocks x 256 thr = 4200 waves (~4.1/SIMD TLP). Channels staged
// 16 at a time into LDS via coalesced float4 loads, double-buffered so chunk
// k+1's HBM latency hides under chunk k's softmax/two-max VALU. LDS column
// reads are stride-256 floats = 2 lanes/bank = conflict-free.
__global__ __launch_bounds__(256) void k_decode(const float* __restrict__ preds,
                                                u64* __restrict__ key_raw,
                                                float4* __restrict__ dbox) {
#pragma clang fp contract(off)
    __shared__ float tile[2][16][256];
    int b = blockIdx.y;
    int a0 = blockIdx.x * 256;
    int t = threadIdx.x;
    int a = a0 + t;
    int nA = A_TOT - a0; if (nA > 256) nA = 256;
    int p4max = nA >> 2;                       // valid float4s per channel row
    const float* pb = preds + (size_t)b * 144 * A_TOT;

    // staging map: float4 index f = t + 256k -> row r=f>>6 (channel), pos p=f&63
    int sr[4], sp[4];
#pragma unroll
    for (int k = 0; k < 4; ++k) { int f = t + 256 * k; sr[k] = f >> 6; sp[k] = f & 63; }

    float4 regs[4];
    auto gload = [&](int ch0) {
#pragma unroll
        for (int k = 0; k < 4; ++k) {
            if (sp[k] < p4max)
                regs[k] = *(const float4*)(pb + (size_t)(ch0 + sr[k]) * A_TOT + a0 + 4 * sp[k]);
            else
                regs[k] = make_float4(0.f, 0.f, 0.f, 0.f);
        }
    };
    auto dswrite = [&](int buf) {
#pragma unroll
        for (int k = 0; k < 4; ++k)
            *(float4*)&tile[buf][sr[k]][4 * sp[k]] = regs[k];
    };

    float d[4] = {0.f, 0.f, 0.f, 0.f};
    float m = -3.0e38f, m2 = -3.0e38f;
    int jm = 0;

    gload(0); dswrite(0); __syncthreads();
    gload(16);                                  // chunk 1 in flight under chunk 0

    for (int cb = 0; cb < 9; ++cb) {
        int buf = cb & 1;
        if (t < nA) {
            float x[16];
#pragma unroll
            for (int r = 0; r < 16; ++r) x[r] = tile[buf][r][t];
            if (cb < 4) {
                // DFL softmax-expectation, exact reference op order
                float mx = x[0];
#pragma unroll
                for (int r = 1; r < 16; ++r) mx = fmaxf(mx, x[r]);
                float e[16], s = 0.f;
#pragma unroll
                for (int r = 0; r < 16; ++r) { e[r] = expf(x[r] - mx); s = s + e[r]; }
                float dd = 0.f;
#pragma unroll
                for (int r = 0; r < 16; ++r) { float pr = e[r] / s; dd = dd + pr * (float)r; }
                d[cb] = dd;
            } else {
                int cbase = (cb - 4) * 16;
#pragma unroll
                for (int r = 0; r < 16; ++r) {
                    int c = cbase + r;
                    float v = x[r];
                    if (v > m) { m2 = m; m = v; jm = c; }
                    else if (v > m2) { m2 = v; }
                }
            }
        }
        if (cb + 1 < 9) {
            __syncthreads();                    // all readers of buf[(cb+1)&1] done
            dswrite((cb + 1) & 1);
            if (cb + 2 < 9) gload((cb + 2) * 16);
            __syncthreads();
        }
    }

    if (t >= nA) return;

    // ----- key (slow exact path rare: tie-gap < 1e-4 or saturated sigmoid) -----
    const float* pc = pb + (size_t)64 * A_TOT + a;
    float conf; int cls = jm;
    if ((m - m2) < 1e-4f || m > 7.0f) {
        float sb = -1.0f; int jb = 0;
        for (int c = 0; c < NCLS; ++c) {
            float s = sig32(pc[(size_t)c * A_TOT]);
            if (s > sb) { sb = s; jb = c; }
        }
        conf = sb; cls = jb;
    } else {
        conf = sig32(m);
    }
    float score = (conf > 0.25f) ? conf : -1.0f;
    u32 hi = key_hi_from_score(score);
    u32 lo = ((0x3FFFu - (u32)a) << 7) | (u32)cls;   // idx asc tie-break + cls
    key_raw[(size_t)b * A_TOT + a] = ((u64)hi << 32) | lo;

    // ----- box from d[0..3], exact reference op order -----
    int row, col; float stride;
    if (a < 6400)      { row = a / 80;          col = a % 80;          stride = 8.0f; }
    else if (a < 8000) { int aa = a - 6400; row = aa / 40; col = aa % 40; stride = 16.0f; }
    else               { int aa = a - 8000; row = aa / 20; col = aa % 20; stride = 32.0f; }
    float ax = (float)col + 0.5f;
    float ay = (float)row + 0.5f;
    float x1 = ax - d[0], y1 = ay - d[1];
    float x2 = ax + d[2], y2 = ay + d[3];
    float cx = (x1 + x2) / 2.0f, cy = (y1 + y2) / 2.0f;
    float w  = x2 - x1,          h  = y2 - y1;
    float4 db;
    db.x = cx * stride; db.y = cy * stride; db.z = w * stride; db.w = h * stride;
    dbox[(size_t)b * A_TOT + a] = db;
}

// ---------- 2a. bitonic sort of 1024-chunks (descending) ----------
__global__ __launch_bounds__(1024) void k_chunksort(const u64* __restrict__ key_raw,
                                                    u64* __restrict__ key_sorted) {
    __shared__ u64 s[KSLOT];
    int b = blockIdx.y, ch = blockIdx.x, t = threadIdx.x;
    int a = ch * KSLOT + t;
    s[t] = (a < A_TOT) ? key_raw[(size_t)b * A_TOT + a] : 0ull;
    __syncthreads();
    for (int k = 2; k <= KSLOT; k <<= 1) {
        for (int j = k >> 1; j > 0; j >>= 1) {
            int ixj = t ^ j;
            if (ixj > t) {
                u64 x = s[t], y = s[ixj];
                bool descBlock = ((t & k) == 0);
                bool sw = descBlock ? (x < y) : (x > y);
                if (sw) { s[t] = y; s[ixj] = x; }
            }
            __syncthreads();
        }
    }
    key_sorted[((size_t)b * NCHUNK + ch) * KSLOT + t] = s[t];
}

// ---------- 2b+3. select: merge-path tree top-1024 + inline prep ----------
// 4 levels of pairwise rank-t merges; 9 barriers total (vs 88 bitonic phases).
// Level 1 reads key_sorted straight from L2/L3 (written just before), levels
// 2-4 run in 40 KB LDS. Tail = former k_prep, input key already in register.
__global__ __launch_bounds__(1024) void k_select(const u64* __restrict__ key_sorted,
                                                 u64* __restrict__ topk,
                                                 const float4* __restrict__ dbox,
                                                 float* __restrict__ tb,
                                                 float* __restrict__ ob,
                                                 float* __restrict__ area,
                                                 u32* __restrict__ validf) {
#pragma clang fp contract(off)
    __shared__ u64 L[5 * KSLOT];                 // 40 KB
    int b = blockIdx.x, t = threadIdx.x;
    const u64* KS = key_sorted + (size_t)b * NCHUNK * KSLOT;

    // Level 1: (0,1) (2,3) (4,5) (6,7) from global; chunk 8 copied
    u64 r0 = mp_rank(KS + 0 * KSLOT, KS + 1 * KSLOT, t);
    u64 r1 = mp_rank(KS + 2 * KSLOT, KS + 3 * KSLOT, t);
    u64 r2 = mp_rank(KS + 4 * KSLOT, KS + 5 * KSLOT, t);
    u64 r3 = mp_rank(KS + 6 * KSLOT, KS + 7 * KSLOT, t);
    u64 r4 = KS[8 * KSLOT + t];
    L[0 * KSLOT + t] = r0; L[1 * KSLOT + t] = r1;
    L[2 * KSLOT + t] = r2; L[3 * KSLOT + t] = r3;
    L[4 * KSLOT + t] = r4;
    __syncthreads();

    // Level 2: (L0,L1)->L0, (L2,L3)->L1
    u64 m0 = mp_rank(L + 0 * KSLOT, L + 1 * KSLOT, t);
    u64 m1 = mp_rank(L + 2 * KSLOT, L + 3 * KSLOT, t);
    __syncthreads();
    L[0 * KSLOT + t] = m0; L[1 * KSLOT + t] = m1;
    __syncthreads();

    // Level 3: (L0,L1)->L0
    u64 s0 = mp_rank(L + 0 * KSLOT, L + 1 * KSLOT, t);
    __syncthreads();
    L[0 * KSLOT + t] = s0;
    __syncthreads();

    // Level 4: (L0, L4=chunk8)
    u64 key = mp_rank(L + 0 * KSLOT, L + 4 * KSLOT, t);
    size_t si = (size_t)b * KSLOT + t;
    topk[si] = key;

    // ----- inline prep (former k_prep, textually identical math) -----
    u32 hi = (u32)(key >> 32);
    u32 lo = (u32)key;
    bool valid = (t < TOPK_N) && (hi & 0x80000000u);
    if (!valid) {
        tb[si*4+0]=0.f; tb[si*4+1]=0.f; tb[si*4+2]=0.f; tb[si*4+3]=0.f;
        ob[si*4+0]=0.f; ob[si*4+1]=0.f; ob[si*4+2]=0.f; ob[si*4+3]=0.f;
        area[si] = 0.f; validf[si] = 0u;
        return;
    }
    int a   = 0x3FFF - (int)((lo >> 7) & 0x3FFFu);
    int cls = (int)(lo & 0x7Fu);

    float4 db = dbox[(size_t)b * A_TOT + a];
    float bx1 = db.x - db.z / 2.0f, by1 = db.y - db.w / 2.0f;
    float bx2 = db.x + db.z / 2.0f, by2 = db.y + db.w / 2.0f;
    tb[si*4+0] = bx1; tb[si*4+1] = by1; tb[si*4+2] = bx2; tb[si*4+3] = by2;

    float off = (float)cls * 7680.0f;
    float o0 = bx1 + off, o1 = by1 + off, o2 = bx2 + off, o3 = by2 + off;
    ob[si*4+0] = o0; ob[si*4+1] = o1; ob[si*4+2] = o2; ob[si*4+3] = o3;
    area[si] = (o2 - o0) * (o3 - o1);
    validf[si] = 1u;
}

// ---------- 4. suppression bitmask matrix: row i, bits j>i with iou>thr ----------
// Lane assignment: lanes of a wave hold consecutive i (register-resident bi),
// w is wave-uniform -> inner-loop sob[j]/sar[j] reads are LDS broadcasts
// (zero bank conflicts). Word-blocks fully below the diagonal are skipped.
__global__ __launch_bounds__(256) void k_matrix(const float* __restrict__ ob,
                                                const float* __restrict__ area,
                                                u64* __restrict__ masks) {
#pragma clang fp contract(off)
    __shared__ float4 sob[KSLOT];
    __shared__ float  sar[KSLOT];
    int b = blockIdx.y, rblk = blockIdx.x, tid = threadIdx.x;
    const float4* gob = (const float4*)(ob + (size_t)b * KSLOT * 4);
    const float*  gar = area + (size_t)b * KSLOT;
    for (int i = tid; i < KSLOT; i += blockDim.x) { sob[i] = gob[i]; sar[i] = gar[i]; }
    __syncthreads();

    int lane = tid & 63;
    int wave = tid >> 6;               // 0..3
    int i = rblk * 64 + lane;
    float4 bi = sob[i];
    float Ai = sar[i];

#pragma unroll
    for (int wl = 0; wl < 4; ++wl) {
        int w = wave * 4 + wl;         // wave-uniform word index 0..15
        u64 mword = 0ull;
        if (w >= rblk) {               // whole word below diagonal -> all zero
            for (int bit = 0; bit < 64; ++bit) {
                int j = (w << 6) + bit;
                float4 bj = sob[j];    // broadcast (uniform addr across wave)
                float Aj = sar[j];     // broadcast
                float lt0 = fmaxf(bi.x, bj.x);
                float lt1 = fmaxf(bi.y, bj.y);
                float rb0 = fminf(bi.z, bj.z);
                float rb1 = fminf(bi.w, bj.w);
                float ww = fmaxf(rb0 - lt0, 0.0f);
                float hh = fmaxf(rb1 - lt1, 0.0f);
                float inter = ww * hh;
                float den = ((Ai + Aj) - inter) + 1e-7f;
                float iou = inter / den;
                if ((j > i) && (iou > 0.45f)) mword |= (1ull << bit);
            }
        }
        masks[((size_t)b * KSLOT + i) * 16 + w] = mword;
    }
}

// ---------- 5. greedy scan: live-mask skip, LDS-staged rows, early stop ----------
// Trip count = number of KEPT boxes (<= 300), not number of candidates.
// Key fact: the lowest live bit is always kept (all earlier kept rows' masks
// already applied), so each serial step commits exactly one kept box.
__global__ __launch_bounds__(64) void k_scan(const u64* __restrict__ masks,
                                             const u32* __restrict__ validf,
                                             u64* __restrict__ keep) {
    __shared__ u64 rows[KSLOT];          // 8KB: current word's 64 rows x 16 words
    int b = blockIdx.x, lane = threadIdx.x;
    const char* base = (const char*)(masks + (size_t)b * KSLOT * 16);

    // prefetch word 0's 8KB block into registers (coalesced dwordx4)
    float4 r0, r1, r2, r3, r4, r5, r6, r7;
    {
        const float4* src = (const float4*)base;
        r0 = src[0*64 + lane]; r1 = src[1*64 + lane];
        r2 = src[2*64 + lane]; r3 = src[3*64 + lane];
        r4 = src[4*64 + lane]; r5 = src[5*64 + lane];
        r6 = src[6*64 + lane]; r7 = src[7*64 + lane];
    }

    u64 kw = 0ull;       // lane l<16 owns keep word l
    u64 rem = 0ull;      // lane l<16 owns removed word l
    int kept = 0;

    for (int w = 0; w < 16; ++w) {
        // stage current word's rows into LDS
        {
            float4* dst = (float4*)rows;
            dst[0*64 + lane] = r0; dst[1*64 + lane] = r1;
            dst[2*64 + lane] = r2; dst[3*64 + lane] = r3;
            dst[4*64 + lane] = r4; dst[5*64 + lane] = r5;
            dst[6*64 + lane] = r6; dst[7*64 + lane] = r7;
        }
        u32 vf = validf[(size_t)b * KSLOT + w * 64 + lane];
        u64 valid_w = __ballot(vf != 0u);
        __syncthreads();
        // issue next word's loads (overlap with the serial scan below)
        if (w < 15) {
            const float4* src = (const float4*)(base + (size_t)(w + 1) * 8192);
            r0 = src[0*64 + lane]; r1 = src[1*64 + lane];
            r2 = src[2*64 + lane]; r3 = src[3*64 + lane];
            r4 = src[4*64 + lane]; r5 = src[5*64 + lane];
            r6 = src[6*64 + lane]; r7 = src[7*64 + lane];
        }

        u64 live = valid_w & ~__shfl(rem, w);
        while (live) {
            int i = __ffsll(live) - 1;           // lowest live slot: always kept
            if (lane == w) kw |= (1ull << i);
            u64 m = (lane < 16) ? rows[i * 16 + lane] : 0ull;
            rem |= m;
            ++kept;
            if (kept >= MAXDET) break;           // only first 300 kept are emitted
            live &= ~(__shfl(m, w) | (1ull << i));
        }
        if (kept >= MAXDET) break;
        __syncthreads();   // all lanes done reading rows before next overwrite
    }
    if (lane < 16) keep[(size_t)b * 16 + lane] = kw;
}

// ---------- 6. finalize: compact kept (ordered) into first 300 rows ----------
__global__ __launch_bounds__(1024) void k_final(const u64* __restrict__ keep,
                                                const u64* __restrict__ topk,
                                                const float* __restrict__ tb,
                                                float* __restrict__ out) {
    __shared__ u64 kw[16];
    __shared__ int pref[16];
    int b = blockIdx.x, t = threadIdx.x;
    float* ob_ = out + (size_t)b * OUT_STRIDE;
    for (int i = t; i < OUT_STRIDE; i += blockDim.x) ob_[i] = 0.0f;
    if (t < 16) kw[t] = keep[(size_t)b * 16 + t];
    __syncthreads();
    if (t == 0) {
        int s = 0;
        for (int w = 0; w < 16; ++w) { pref[w] = s; s += __popcll(kw[w]); }
    }
    __syncthreads();
    int w = t >> 6, bit = t & 63;
    bool kp = (kw[w] >> bit) & 1ull;
    if (kp) {
        u64 below = (bit == 0) ? 0ull : (kw[w] & ((1ull << bit) - 1ull));
        int rank = pref[w] + __popcll(below);
        if (rank < MAXDET) {
            size_t si = (size_t)b * KSLOT + t;
            u64 key = topk[si];
            u32 hi = (u32)(key >> 32);
            u32 lo = (u32)key;
            float score = score_from_key_hi(hi);
            float clsf = (float)(lo & 0x7Fu);
            float* o = ob_ + rank * 6;
            o[0] = tb[si*4+0]; o[1] = tb[si*4+1];
            o[2] = tb[si*4+2]; o[3] = tb[si*4+3];
            o[4] = score; o[5] = clsf;
        }
    }
}

// ---------- launch ----------
extern "C" void kernel_launch(void* const* d_in, const int* in_sizes, int n_in,
                              void* d_out, int out_size, void* d_ws, size_t ws_size,
                              hipStream_t stream) {
    const float* preds = (const float*)d_in[0];
    float* out = (float*)d_out;
    int B = in_sizes[0] / (144 * A_TOT);

    char* ws = (char*)d_ws;
    size_t off = 0;
    u64* key_raw    = (u64*)(ws + off); off += (size_t)B * A_TOT * 8;
    u64* key_sorted = (u64*)(ws + off); off += (size_t)B * NCHUNK * KSLOT * 8;
    u64* topk       = (u64*)(ws + off); off += (size_t)B * KSLOT * 8;
    float4* dbox    = (float4*)(ws + off); off += (size_t)B * A_TOT * 16;
    float* tb       = (float*)(ws + off); off += (size_t)B * KSLOT * 4 * 4;
    float* obuf     = (float*)(ws + off); off += (size_t)B * KSLOT * 4 * 4;
    float* area     = (float*)(ws + off); off += (size_t)B * KSLOT * 4;
    u32* validf     = (u32*)(ws + off); off += (size_t)B * KSLOT * 4;
    u64* masks      = (u64*)(ws + off); off += (size_t)B * KSLOT * 16 * 8;
    u64* keep       = (u64*)(ws + off); off += (size_t)B * 16 * 8;

    k_decode<<<dim3((A_TOT + 255) / 256, B), 256, 0, stream>>>(preds, key_raw, dbox);
    k_chunksort<<<dim3(NCHUNK, B), KSLOT, 0, stream>>>(key_raw, key_sorted);
    k_select<<<B, KSLOT, 0, stream>>>(key_sorted, topk, dbox, tb, obuf, area, validf);
    k_matrix<<<dim3(16, B), 256, 0, stream>>>(obuf, area, masks);
    k_scan<<<B, 64, 0, stream>>>(masks, validf, keep);
    k_final<<<B, 1024, 0, stream>>>(keep, topk, tb, out);
}

// Round 9
// 165.832 us; speedup vs baseline: 1.2311x; 1.0097x over previous
//
#include <hip/hip_runtime.h>
#include <cstdint>
#include <cstddef>

typedef unsigned long long u64;
typedef unsigned int u32;

#define A_TOT   8400
#define NCLS    80
#define KSLOT   1024
#define NCHUNK  9
#define TOPK_N  1000
#define MAXDET  300
#define OUT_STRIDE (MAXDET * 6)

#define GLOBAL_AS const __attribute__((address_space(1))) void*
#define LDS_AS __attribute__((address_space(3))) void*

// ---------- helpers ----------

// stepwise f32 sigmoid with correctly-rounded f32 exp (via f64):
// e = fl32(exp(-x)); s = 1/(1+e)   -- replicates np-f32 semantics
__device__ __forceinline__ float sig32(float x) {
#pragma clang fp contract(off)
    float e = (float)exp(-(double)x);
    float t = 1.0f + e;
    return 1.0f / t;
}

__device__ __forceinline__ u32 key_hi_from_score(float s) {
    u32 u = __float_as_uint(s);
    return (u & 0x80000000u) ? ~u : (u | 0x80000000u);
}
__device__ __forceinline__ float score_from_key_hi(u32 t) {
    u32 u = (t & 0x80000000u) ? (t ^ 0x80000000u) : ~t;
    return __uint_as_float(u);
}

// merge-path: element of rank t (0-based) in the descending merge of two
// descending length-1024 lists A, B (t < 1024). Values across A and B are
// distinct wherever it matters (unique anchor index in low bits; zero-pads
// only ever meet strictly-positive real keys), so strict '>' is exact.
__device__ __forceinline__ u64 mp_rank(const u64* __restrict__ A,
                                       const u64* __restrict__ B, int t) {
    int lo = 0, hi = t;
    while (lo < hi) {                     // find max i with (i==0 || A[i-1] > B[t-i])
        int mid = (lo + hi + 1) >> 1;
        if (A[mid - 1] > B[t - mid]) lo = mid; else hi = mid - 1;
    }
    int i = lo, j = t - lo;               // i,j <= t < 1024: A[i], B[j] always valid
    u64 av = A[i], bv = B[j];
    return av > bv ? av : bv;
}

// ---------- 1. fused decode: global_load_lds staging, 1 anchor/thread ----------
// Staging via __builtin_amdgcn_global_load_lds width=16: HBM->LDS direct, no
// VGPR round-trip, no ds_write, ONE barrier per chunk (syncthreads drains
// vmcnt). LDS dest = wave-uniform row base + lane*16: wave w, slot k -> row
// 4k+w, lane l -> bytes [16l,16l+16). Tail block: per-lane global address
// clamped in-bounds (duplicate reads land in LDS slots compute never reads).
__global__ __launch_bounds__(256) void k_decode(const float* __restrict__ preds,
                                                u64* __restrict__ key_raw,
                                                float4* __restrict__ dbox) {
#pragma clang fp contract(off)
    __shared__ float tile[2][16][256];
    int b = blockIdx.y;
    int a0 = blockIdx.x * 256;
    int t = threadIdx.x;
    int a = a0 + t;
    int nA = A_TOT - a0; if (nA > 256) nA = 256;
    int p4max = nA >> 2;                       // valid float4s per channel row
    const float* pb = preds + (size_t)b * 144 * A_TOT;

    int l  = t & 63;                           // lane
    int wv = t >> 6;                           // wave 0..3
    int lc = (l < p4max) ? l : (p4max - 1);    // tail-safe clamped lane pos

    auto stage = [&](int ch0, int buf) {
#pragma unroll
        for (int k = 0; k < 4; ++k) {
            int r = 4 * k + wv;                // wave-uniform row
            const float* gsrc = pb + (size_t)(ch0 + r) * A_TOT + a0 + 4 * lc;
            __builtin_amdgcn_global_load_lds((GLOBAL_AS)gsrc,
                                             (LDS_AS)&tile[buf][r][0],
                                             16, 0, 0);
        }
    };

    float d[4] = {0.f, 0.f, 0.f, 0.f};
    float m = -3.0e38f, m2 = -3.0e38f;
    int jm = 0;

    stage(0, 0);
    __syncthreads();                           // chunk 0 resident

    for (int cb = 0; cb < 9; ++cb) {
        int buf = cb & 1;
        if (cb + 1 < 9) stage((cb + 1) * 16, (cb + 1) & 1);   // overlap with compute
        if (t < nA) {
            float x[16];
#pragma unroll
            for (int r = 0; r < 16; ++r) x[r] = tile[buf][r][t];
            if (cb < 4) {
                // DFL softmax-expectation, exact reference op order
                float mx = x[0];
#pragma unroll
                for (int r = 1; r < 16; ++r) mx = fmaxf(mx, x[r]);
                float e[16], s = 0.f;
#pragma unroll
                for (int r = 0; r < 16; ++r) { e[r] = expf(x[r] - mx); s = s + e[r]; }
                float dd = 0.f;
#pragma unroll
                for (int r = 0; r < 16; ++r) { float pr = e[r] / s; dd = dd + pr * (float)r; }
                d[cb] = dd;
            } else {
                int cbase = (cb - 4) * 16;
#pragma unroll
                for (int r = 0; r < 16; ++r) {
                    int c = cbase + r;
                    float v = x[r];
                    if (v > m) { m2 = m; m = v; jm = c; }
                    else if (v > m2) { m2 = v; }
                }
            }
        }
        if (cb < 8) __syncthreads();           // drains vmcnt: next chunk resident,
    }                                          // and all readers of next buf done

    if (t >= nA) return;

    // ----- key (slow exact path rare: tie-gap < 1e-4 or saturated sigmoid) -----
    const float* pc = pb + (size_t)64 * A_TOT + a;
    float conf; int cls = jm;
    if ((m - m2) < 1e-4f || m > 7.0f) {
        float sb = -1.0f; int jb = 0;
        for (int c = 0; c < NCLS; ++c) {
            float s = sig32(pc[(size_t)c * A_TOT]);
            if (s > sb) { sb = s; jb = c; }
        }
        conf = sb; cls = jb;
    } else {
        conf = sig32(m);
    }
    float score = (conf > 0.25f) ? conf : -1.0f;
    u32 hi = key_hi_from_score(score);
    u32 lo = ((0x3FFFu - (u32)a) << 7) | (u32)cls;   // idx asc tie-break + cls
    key_raw[(size_t)b * A_TOT + a] = ((u64)hi << 32) | lo;

    // ----- box from d[0..3], exact reference op order -----
    int row, col; float stride;
    if (a < 6400)      { row = a / 80;          col = a % 80;          stride = 8.0f; }
    else if (a < 8000) { int aa = a - 6400; row = aa / 40; col = aa % 40; stride = 16.0f; }
    else               { int aa = a - 8000; row = aa / 20; col = aa % 20; stride = 32.0f; }
    float ax = (float)col + 0.5f;
    float ay = (float)row + 0.5f;
    float x1 = ax - d[0], y1 = ay - d[1];
    float x2 = ax + d[2], y2 = ay + d[3];
    float cx = (x1 + x2) / 2.0f, cy = (y1 + y2) / 2.0f;
    float w  = x2 - x1,          h  = y2 - y1;
    float4 db;
    db.x = cx * stride; db.y = cy * stride; db.z = w * stride; db.w = h * stride;
    dbox[(size_t)b * A_TOT + a] = db;
}

// ---------- 2a. bitonic sort of 1024-chunks (descending) ----------
__global__ __launch_bounds__(1024) void k_chunksort(const u64* __restrict__ key_raw,
                                                    u64* __restrict__ key_sorted) {
    __shared__ u64 s[KSLOT];
    int b = blockIdx.y, ch = blockIdx.x, t = threadIdx.x;
    int a = ch * KSLOT + t;
    s[t] = (a < A_TOT) ? key_raw[(size_t)b * A_TOT + a] : 0ull;
    __syncthreads();
    for (int k = 2; k <= KSLOT; k <<= 1) {
        for (int j = k >> 1; j > 0; j >>= 1) {
            int ixj = t ^ j;
            if (ixj > t) {
                u64 x = s[t], y = s[ixj];
                bool descBlock = ((t & k) == 0);
                bool sw = descBlock ? (x < y) : (x > y);
                if (sw) { s[t] = y; s[ixj] = x; }
            }
            __syncthreads();
        }
    }
    key_sorted[((size_t)b * NCHUNK + ch) * KSLOT + t] = s[t];
}

// ---------- 2b+3. select: merge-path tree top-1024 + inline prep ----------
// 4 levels of pairwise rank-t merges; 9 barriers total (vs 88 bitonic phases).
__global__ __launch_bounds__(1024) void k_select(const u64* __restrict__ key_sorted,
                                                 u64* __restrict__ topk,
                                                 const float4* __restrict__ dbox,
                                                 float* __restrict__ tb,
                                                 float* __restrict__ ob,
                                                 float* __restrict__ area,
                                                 u32* __restrict__ validf) {
#pragma clang fp contract(off)
    __shared__ u64 L[5 * KSLOT];                 // 40 KB
    int b = blockIdx.x, t = threadIdx.x;
    const u64* KS = key_sorted + (size_t)b * NCHUNK * KSLOT;

    // Level 1: (0,1) (2,3) (4,5) (6,7) from global; chunk 8 copied
    u64 r0 = mp_rank(KS + 0 * KSLOT, KS + 1 * KSLOT, t);
    u64 r1 = mp_rank(KS + 2 * KSLOT, KS + 3 * KSLOT, t);
    u64 r2 = mp_rank(KS + 4 * KSLOT, KS + 5 * KSLOT, t);
    u64 r3 = mp_rank(KS + 6 * KSLOT, KS + 7 * KSLOT, t);
    u64 r4 = KS[8 * KSLOT + t];
    L[0 * KSLOT + t] = r0; L[1 * KSLOT + t] = r1;
    L[2 * KSLOT + t] = r2; L[3 * KSLOT + t] = r3;
    L[4 * KSLOT + t] = r4;
    __syncthreads();

    // Level 2: (L0,L1)->L0, (L2,L3)->L1
    u64 m0 = mp_rank(L + 0 * KSLOT, L + 1 * KSLOT, t);
    u64 m1 = mp_rank(L + 2 * KSLOT, L + 3 * KSLOT, t);
    __syncthreads();
    L[0 * KSLOT + t] = m0; L[1 * KSLOT + t] = m1;
    __syncthreads();

    // Level 3: (L0,L1)->L0
    u64 s0 = mp_rank(L + 0 * KSLOT, L + 1 * KSLOT, t);
    __syncthreads();
    L[0 * KSLOT + t] = s0;
    __syncthreads();

    // Level 4: (L0, L4=chunk8)
    u64 key = mp_rank(L + 0 * KSLOT, L + 4 * KSLOT, t);
    size_t si = (size_t)b * KSLOT + t;
    topk[si] = key;

    // ----- inline prep (former k_prep, textually identical math) -----
    u32 hi = (u32)(key >> 32);
    u32 lo = (u32)key;
    bool valid = (t < TOPK_N) && (hi & 0x80000000u);
    if (!valid) {
        tb[si*4+0]=0.f; tb[si*4+1]=0.f; tb[si*4+2]=0.f; tb[si*4+3]=0.f;
        ob[si*4+0]=0.f; ob[si*4+1]=0.f; ob[si*4+2]=0.f; ob[si*4+3]=0.f;
        area[si] = 0.f; validf[si] = 0u;
        return;
    }
    int a   = 0x3FFF - (int)((lo >> 7) & 0x3FFFu);
    int cls = (int)(lo & 0x7Fu);

    float4 db = dbox[(size_t)b * A_TOT + a];
    float bx1 = db.x - db.z / 2.0f, by1 = db.y - db.w / 2.0f;
    float bx2 = db.x + db.z / 2.0f, by2 = db.y + db.w / 2.0f;
    tb[si*4+0] = bx1; tb[si*4+1] = by1; tb[si*4+2] = bx2; tb[si*4+3] = by2;

    float off = (float)cls * 7680.0f;
    float o0 = bx1 + off, o1 = by1 + off, o2 = bx2 + off, o3 = by2 + off;
    ob[si*4+0] = o0; ob[si*4+1] = o1; ob[si*4+2] = o2; ob[si*4+3] = o3;
    area[si] = (o2 - o0) * (o3 - o1);
    validf[si] = 1u;
}

// ---------- 4. suppression bitmask matrix: row i, bits j>i with iou>thr ----------
__global__ __launch_bounds__(256) void k_matrix(const float* __restrict__ ob,
                                                const float* __restrict__ area,
                                                u64* __restrict__ masks) {
#pragma clang fp contract(off)
    __shared__ float4 sob[KSLOT];
    __shared__ float  sar[KSLOT];
    int b = blockIdx.y, rblk = blockIdx.x, tid = threadIdx.x;
    const float4* gob = (const float4*)(ob + (size_t)b * KSLOT * 4);
    const float*  gar = area + (size_t)b * KSLOT;
    for (int i = tid; i < KSLOT; i += blockDim.x) { sob[i] = gob[i]; sar[i] = gar[i]; }
    __syncthreads();

    int lane = tid & 63;
    int wave = tid >> 6;               // 0..3
    int i = rblk * 64 + lane;
    float4 bi = sob[i];
    float Ai = sar[i];

#pragma unroll
    for (int wl = 0; wl < 4; ++wl) {
        int w = wave * 4 + wl;         // wave-uniform word index 0..15
        u64 mword = 0ull;
        if (w >= rblk) {               // whole word below diagonal -> all zero
            for (int bit = 0; bit < 64; ++bit) {
                int j = (w << 6) + bit;
                float4 bj = sob[j];    // broadcast (uniform addr across wave)
                float Aj = sar[j];     // broadcast
                float lt0 = fmaxf(bi.x, bj.x);
                float lt1 = fmaxf(bi.y, bj.y);
                float rb0 = fminf(bi.z, bj.z);
                float rb1 = fminf(bi.w, bj.w);
                float ww = fmaxf(rb0 - lt0, 0.0f);
                float hh = fmaxf(rb1 - lt1, 0.0f);
                float inter = ww * hh;
                float den = ((Ai + Aj) - inter) + 1e-7f;
                float iou = inter / den;
                if ((j > i) && (iou > 0.45f)) mword |= (1ull << bit);
            }
        }
        masks[((size_t)b * KSLOT + i) * 16 + w] = mword;
    }
}

// ---------- 5. greedy scan: live-mask skip, LDS-staged rows, early stop ----------
__global__ __launch_bounds__(64) void k_scan(const u64* __restrict__ masks,
                                             const u32* __restrict__ validf,
                                             u64* __restrict__ keep) {
    __shared__ u64 rows[KSLOT];          // 8KB: current word's 64 rows x 16 words
    int b = blockIdx.x, lane = threadIdx.x;
    const char* base = (const char*)(masks + (size_t)b * KSLOT * 16);

    // prefetch word 0's 8KB block into registers (coalesced dwordx4)
    float4 r0, r1, r2, r3, r4, r5, r6, r7;
    {
        const float4* src = (const float4*)base;
        r0 = src[0*64 + lane]; r1 = src[1*64 + lane];
        r2 = src[2*64 + lane]; r3 = src[3*64 + lane];
        r4 = src[4*64 + lane]; r5 = src[5*64 + lane];
        r6 = src[6*64 + lane]; r7 = src[7*64 + lane];
    }

    u64 kw = 0ull;       // lane l<16 owns keep word l
    u64 rem = 0ull;      // lane l<16 owns removed word l
    int kept = 0;

    for (int w = 0; w < 16; ++w) {
        // stage current word's rows into LDS
        {
            float4* dst = (float4*)rows;
            dst[0*64 + lane] = r0; dst[1*64 + lane] = r1;
            dst[2*64 + lane] = r2; dst[3*64 + lane] = r3;
            dst[4*64 + lane] = r4; dst[5*64 + lane] = r5;
            dst[6*64 + lane] = r6; dst[7*64 + lane] = r7;
        }
        u32 vf = validf[(size_t)b * KSLOT + w * 64 + lane];
        u64 valid_w = __ballot(vf != 0u);
        __syncthreads();
        // issue next word's loads (overlap with the serial scan below)
        if (w < 15) {
            const float4* src = (const float4*)(base + (size_t)(w + 1) * 8192);
            r0 = src[0*64 + lane]; r1 = src[1*64 + lane];
            r2 = src[2*64 + lane]; r3 = src[3*64 + lane];
            r4 = src[4*64 + lane]; r5 = src[5*64 + lane];
            r6 = src[6*64 + lane]; r7 = src[7*64 + lane];
        }

        u64 live = valid_w & ~__shfl(rem, w);
        while (live) {
            int i = __ffsll(live) - 1;           // lowest live slot: always kept
            if (lane == w) kw |= (1ull << i);
            u64 m = (lane < 16) ? rows[i * 16 + lane] : 0ull;
            rem |= m;
            ++kept;
            if (kept >= MAXDET) break;           // only first 300 kept are emitted
            live &= ~(__shfl(m, w) | (1ull << i));
        }
        if (kept >= MAXDET) break;
        __syncthreads();   // all lanes done reading rows before next overwrite
    }
    if (lane < 16) keep[(size_t)b * 16 + lane] = kw;
}

// ---------- 6. finalize: compact kept (ordered) into first 300 rows ----------
__global__ __launch_bounds__(1024) void k_final(const u64* __restrict__ keep,
                                                const u64* __restrict__ topk,
                                                const float* __restrict__ tb,
                                                float* __restrict__ out) {
    __shared__ u64 kw[16];
    __shared__ int pref[16];
    int b = blockIdx.x, t = threadIdx.x;
    float* ob_ = out + (size_t)b * OUT_STRIDE;
    for (int i = t; i < OUT_STRIDE; i += blockDim.x) ob_[i] = 0.0f;
    if (t < 16) kw[t] = keep[(size_t)b * 16 + t];
    __syncthreads();
    if (t == 0) {
        int s = 0;
        for (int w = 0; w < 16; ++w) { pref[w] = s; s += __popcll(kw[w]); }
    }
    __syncthreads();
    int w = t >> 6, bit = t & 63;
    bool kp = (kw[w] >> bit) & 1ull;
    if (kp) {
        u64 below = (bit == 0) ? 0ull : (kw[w] & ((1ull << bit) - 1ull));
        int rank = pref[w] + __popcll(below);
        if (rank < MAXDET) {
            size_t si = (size_t)b * KSLOT + t;
            u64 key = topk[si];
            u32 hi = (u32)(key >> 32);
            u32 lo = (u32)key;
            float score = score_from_key_hi(hi);
            float clsf = (float)(lo & 0x7Fu);
            float* o = ob_ + rank * 6;
            o[0] = tb[si*4+0]; o[1] = tb[si*4+1];
            o[2] = tb[si*4+2]; o[3] = tb[si*4+3];
            o[4] = score; o[5] = clsf;
        }
    }
}

// ---------- launch ----------
extern "C" void kernel_launch(void* const* d_in, const int* in_sizes, int n_in,
                              void* d_out, int out_size, void* d_ws, size_t ws_size,
                              hipStream_t stream) {
    const float* preds = (const float*)d_in[0];
    float* out = (float*)d_out;
    int B = in_sizes[0] / (144 * A_TOT);

    char* ws = (char*)d_ws;
    size_t off = 0;
    u64* key_raw    = (u64*)(ws + off); off += (size_t)B * A_TOT * 8;
    u64* key_sorted = (u64*)(ws + off); off += (size_t)B * NCHUNK * KSLOT * 8;
    u64* topk       = (u64*)(ws + off); off += (size_t)B * KSLOT * 8;
    float4* dbox    = (float4*)(ws + off); off += (size_t)B * A_TOT * 16;
    float* tb       = (float*)(ws + off); off += (size_t)B * KSLOT * 4 * 4;
    float* obuf     = (float*)(ws + off); off += (size_t)B * KSLOT * 4 * 4;
    float* area     = (float*)(ws + off); off += (size_t)B * KSLOT * 4;
    u32* validf     = (u32*)(ws + off); off += (size_t)B * KSLOT * 4;
    u64* masks      = (u64*)(ws + off); off += (size_t)B * KSLOT * 16 * 8;
    u64* keep       = (u64*)(ws + off); off += (size_t)B * 16 * 8;

    k_decode<<<dim3((A_TOT + 255) / 256, B), 256, 0, stream>>>(preds, key_raw, dbox);
    k_chunksort<<<dim3(NCHUNK, B), KSLOT, 0, stream>>>(key_raw, key_sorted);
    k_select<<<B, KSLOT, 0, stream>>>(key_sorted, topk, dbox, tb, obuf, area, validf);
    k_matrix<<<dim3(16, B), 256, 0, stream>>>(obuf, area, masks);
    k_scan<<<B, 64, 0, stream>>>(masks, validf, keep);
    k_final<<<B, 1024, 0, stream>>>(keep, topk, tb, out);
}